// Round 2
// baseline (1259.702 us; speedup 1.0000x reference)
//
#include <hip/hip_runtime.h>
#include <cmath>
#include <cstdint>

// Problem constants
#define B_N  64
#define W_N  16
#define C_N  64
#define T_N  1024
#define BW_N 1024           // B*W
#define DE_N 64
#define AIDX(i,j) ((i)*65 + (j))   // +1 pad (stride 65) to break stride-64 LDS bank conflicts

// ---------------------------------------------------------------------------
// K1: per-(b,w,c) stats over T.  One wave per row of 1024 floats.
// stat = 0.5*(mean + energy), accumulated in fp64, stored transposed [C][BW].
// ---------------------------------------------------------------------------
__global__ __launch_bounds__(256) void k_stats(const float* __restrict__ x,
                                               double* __restrict__ statT) {
  int wid  = (blockIdx.x << 2) + (threadIdx.x >> 6);  // row id = bw*64 + c, 0..65535
  int lane = threadIdx.x & 63;
  const float4* xp = (const float4*)(x + (size_t)wid * T_N);
  double s = 0.0, q = 0.0;
#pragma unroll
  for (int k = 0; k < 4; ++k) {
    float4 v = xp[lane + (k << 6)];
    double a0 = v.x, a1 = v.y, a2 = v.z, a3 = v.w;
    s += (a0 + a1) + (a2 + a3);
    q += (a0*a0 + a1*a1) + (a2*a2 + a3*a3);
  }
#pragma unroll
  for (int off = 32; off; off >>= 1) {
    s += __shfl_down(s, off, 64);
    q += __shfl_down(q, off, 64);
  }
  if (lane == 0) {
    int bw = wid >> 6, c = wid & 63;
    statT[c * BW_N + bw] = 0.5 * (s * (1.0 / T_N) + q * (1.0 / T_N));
  }
}

// ---------------------------------------------------------------------------
// K2: Z[c][e] = mean_{bw} tanh(stat[bw][c] * Wp[e]).  One wave per (c,e).
// ---------------------------------------------------------------------------
__global__ __launch_bounds__(256) void k_embed(const double* __restrict__ statT,
                                               const float* __restrict__ Wp,
                                               double* __restrict__ Z) {
  int wid  = (blockIdx.x << 2) + (threadIdx.x >> 6);  // 0..4095
  int lane = threadIdx.x & 63;
  int c = wid >> 6, e = wid & 63;
  double wpe = (double)Wp[e];
  const double* sp = statT + c * BW_N;
  double s = 0.0;
#pragma unroll
  for (int k = 0; k < 16; ++k) s += tanh(sp[lane + (k << 6)] * wpe);
#pragma unroll
  for (int off = 32; off; off >>= 1) s += __shfl_down(s, off, 64);
  if (lane == 0) Z[c * 64 + e] = s * (1.0 / 1024.0);
}

// ---------------------------------------------------------------------------
// K3: single-block graph construction: D2, 2 refine steps, exact JAX threefry
// (PARTITIONABLE scheme — default since JAX 0.4.30) gumbel top-k, sym degree
// norm, outputs A_final (fp32) and A2 = A*A (fp32).
// All in fp64 to track the numpy reference through the hard top-k selection.
// ---------------------------------------------------------------------------
__device__ __forceinline__ unsigned rotl32(unsigned v, unsigned d) {
  return (v << d) | (v >> (32u - d));
}

// JAX partitionable threefry2x32-20, key = (0, 42).
// Element m: counter = uint64(m) -> (hi, lo) = (0, m); inputs
// x0 = hi + k0, x1 = lo + k1; output = x0_out ^ x1_out.
__device__ __forceinline__ unsigned threefry_bits(unsigned m) {
  const unsigned k0 = 0u, k1 = 42u, k2 = 0x1BD11BDAu ^ k0 ^ k1;
  unsigned x0 = 0u + k0;   // counts_hi + k0
  unsigned x1 = m + k1;    // counts_lo + k1
#define TF_R4(a,b,c,d) \
  x0 += x1; x1 = rotl32(x1,a); x1 ^= x0; \
  x0 += x1; x1 = rotl32(x1,b); x1 ^= x0; \
  x0 += x1; x1 = rotl32(x1,c); x1 ^= x0; \
  x0 += x1; x1 = rotl32(x1,d); x1 ^= x0;
  TF_R4(13,15,26,6)  x0 += k1; x1 += k2 + 1u;
  TF_R4(17,29,16,24) x0 += k2; x1 += k0 + 2u;
  TF_R4(13,15,26,6)  x0 += k0; x1 += k1 + 3u;
  TF_R4(17,29,16,24) x0 += k1; x1 += k2 + 4u;
  TF_R4(13,15,26,6)  x0 += k2; x1 += k0 + 5u;
#undef TF_R4
  return x0 ^ x1;
}

__device__ __forceinline__ double softplus_d(double x) {
  return (x > 0.0) ? x + log1p(exp(-x)) : log1p(exp(x));
}

__global__ __launch_bounds__(1024) void k_graph(
    const double* __restrict__ Z,
    const float* __restrict__ w1, const float* __restrict__ b1,
    const float* __restrict__ w2, const float* __restrict__ b2,
    const float* __restrict__ beta_p, const float* __restrict__ gres_p,
    const float* __restrict__ temp_p,
    float* __restrict__ Aout, float* __restrict__ A2out) {
  __shared__ double As[64 * 65];   // Z, then A (stride-65 padded)
  __shared__ float  Af[64 * 65];   // A_final in fp32 for the A2 matmul
  __shared__ double sq[64];
  __shared__ double dinv[64];

  int tid  = threadIdx.x;
  int i_   = tid >> 4;           // 0..63
  int j0   = (tid & 15) << 2;    // 0,4,...,60  (thread owns entries (i_, j0..j0+3))
  int wv   = tid >> 6;           // wave 0..15
  int lane = tid & 63;

  // stage Z into padded LDS
#pragma unroll
  for (int u = 0; u < 4; ++u) As[AIDX(i_, j0 + u)] = Z[(i_ << 6) + j0 + u];
  __syncthreads();

  if (tid < 64) {
    double s = 0.0;
    for (int e = 0; e < 64; ++e) { double z = As[AIDX(tid, e)]; s += z * z; }
    sq[tid] = s;
  }
  __syncthreads();

  // D2 into registers (kept for both refine steps)
  double d2r[4];
  {
    double dot[4] = {0.0, 0.0, 0.0, 0.0};
    for (int e = 0; e < 64; ++e) {
      double zi = As[AIDX(i_, e)];
#pragma unroll
      for (int u = 0; u < 4; ++u) dot[u] += zi * As[AIDX(j0 + u, e)];
    }
#pragma unroll
    for (int u = 0; u < 4; ++u) {
      double v = sq[i_] + sq[j0 + u] - 2.0 * dot[u];
      d2r[u] = (v > 0.0 ? v : 0.0) * 0.5;
    }
  }
  __syncthreads();

  // A = I
#pragma unroll
  for (int u = 0; u < 4; ++u) As[AIDX(i_, j0 + u)] = (i_ == j0 + u) ? 1.0 : 0.0;
  __syncthreads();

  double beta = (double)beta_p[0], gres = (double)gres_p[0];
  double temp = (double)temp_p[0];
  double tclip = temp > 1e-6 ? temp : 1e-6;
  double b2d = (double)b2[0];
  const double inv_sqrt2 = 0.70710678118654752440;

  // two refinement steps
  for (int step = 0; step < 2; ++step) {
    double nv[4];
#pragma unroll
    for (int u = 0; u < 4; ++u) {
      double a = As[AIDX(i_, j0 + u)] - 0.2 * d2r[u];
      double acc = b2d;
#pragma unroll
      for (int k = 0; k < 16; ++k) {
        double zz = a * (double)w1[k] + (double)b1[k];
        double h  = 0.5 * zz * (1.0 + erf(zz * inv_sqrt2));
        acc += h * (double)w2[k];
      }
      nv[u] = a + beta * (softplus_d(acc) * gres);
    }
#pragma unroll
    for (int u = 0; u < 4; ++u) As[AIDX(i_, j0 + u)] = nv[u];
    __syncthreads();
    // sym, relu, +I
#pragma unroll
    for (int u = 0; u < 4; ++u)
      nv[u] = 0.5 * (As[AIDX(i_, j0 + u)] + As[AIDX(j0 + u, i_)]);
    __syncthreads();
#pragma unroll
    for (int u = 0; u < 4; ++u) {
      double v = nv[u] > 0.0 ? nv[u] : 0.0;
      if (i_ == j0 + u) v += 1.0;
      As[AIDX(i_, j0 + u)] = v;
    }
    __syncthreads();
  }

  // Gumbel top-k mask (wave wv owns rows 4wv..4wv+3; lane = column)
  double maskedv[4];
#pragma unroll
  for (int rr = 0; rr < 4; ++rr) {
    int r = (wv << 2) + rr;
    unsigned m = (unsigned)((r << 6) + lane);
    unsigned bits = threefry_bits(m);
    float uf = __uint_as_float((bits >> 9) | 0x3f800000u) - 1.0f;
    if (uf == 0.0f) uf = 1.17549435e-38f;            // minval = finfo(f32).tiny
    float gf = -logf(-logf(uf));                     // fp32, as JAX computes it
    double g = (double)gf;
    double aval = As[AIDX(r, lane)];
    double val  = (aval + g) / tclip;
    bool keep = false;
    for (int it = 0; it < 16; ++it) {
      double bv = val; int bi = lane;
#pragma unroll
      for (int off = 32; off; off >>= 1) {
        double ov = __shfl_xor(bv, off, 64);
        int    oi = __shfl_xor(bi, off, 64);
        if (ov > bv || (ov == bv && oi < bi)) { bv = ov; bi = oi; }
      }
      if (lane == bi) { keep = true; val = -1e300; }
    }
    maskedv[rr] = keep ? aval : 0.0;
  }
  __syncthreads();
#pragma unroll
  for (int rr = 0; rr < 4; ++rr) As[AIDX((wv << 2) + rr, lane)] = maskedv[rr];
  __syncthreads();

  // A = relu(0.5*(A+A^T)) + I
  {
    double nv[4];
#pragma unroll
    for (int u = 0; u < 4; ++u)
      nv[u] = 0.5 * (As[AIDX(i_, j0 + u)] + As[AIDX(j0 + u, i_)]);
    __syncthreads();
#pragma unroll
    for (int u = 0; u < 4; ++u) {
      double v = nv[u] > 0.0 ? nv[u] : 0.0;
      if (i_ == j0 + u) v += 1.0;
      As[AIDX(i_, j0 + u)] = v;
    }
    __syncthreads();
  }

  // degree normalization
#pragma unroll
  for (int rr = 0; rr < 4; ++rr) {
    int r = (wv << 2) + rr;
    double s = As[AIDX(r, lane)];
#pragma unroll
    for (int off = 32; off; off >>= 1) s += __shfl_xor(s, off, 64);
    if (lane == 0) { double cs = s > 1e-6 ? s : 1e-6; dinv[r] = 1.0 / sqrt(cs); }
  }
  __syncthreads();

  // A_final = dinv_i * A * dinv_j + I ; emit fp32 copies
#pragma unroll
  for (int u = 0; u < 4; ++u) {
    double v = dinv[i_] * As[AIDX(i_, j0 + u)] * dinv[j0 + u];
    if (i_ == j0 + u) v += 1.0;
    float vf = (float)v;
    Af[AIDX(i_, j0 + u)] = vf;
    Aout[(i_ << 6) + j0 + u] = vf;
  }
  __syncthreads();

  // A2 = A_final @ A_final  (fp32 — feeds the fp32 propagation)
  {
    float acc[4] = {0.f, 0.f, 0.f, 0.f};
    for (int k = 0; k < 64; ++k) {
      float aik = Af[AIDX(i_, k)];
#pragma unroll
      for (int u = 0; u < 4; ++u) acc[u] += aik * Af[AIDX(k, j0 + u)];
    }
#pragma unroll
    for (int u = 0; u < 4; ++u) A2out[(i_ << 6) + j0 + u] = acc[u];
  }
}

// ---------------------------------------------------------------------------
// K4: out[b,c,w*T+t] = sum_j A2[c,j] * x[b,w,j,t]
// lane = t; xv[64] in VGPRs (coalesced); A2 rows via wave-uniform scalar loads.
// ---------------------------------------------------------------------------
__device__ __forceinline__ const float* uniform_ptr(const float* p) {
  unsigned long long v = (unsigned long long)p;
  unsigned lo = __builtin_amdgcn_readfirstlane((unsigned)v);
  unsigned hi = __builtin_amdgcn_readfirstlane((unsigned)(v >> 32));
  return (const float*)(((unsigned long long)hi << 32) | (unsigned long long)lo);
}

__global__ __launch_bounds__(256) void k_prop(const float* __restrict__ x,
                                              const float* __restrict__ A2,
                                              float* __restrict__ out) {
  int bw   = blockIdx.x >> 2;          // 0..1023  (= b*16 + w)
  int tq   = blockIdx.x & 3;
  int wv   = threadIdx.x >> 6;
  int lane = threadIdx.x & 63;
  int t0   = (tq << 8) + (wv << 6);    // 0,64,...,960

  const float* xp = x + ((size_t)bw << 16) + (size_t)(t0 + lane);
  float xv[64];
#pragma unroll
  for (int j = 0; j < 64; ++j) xv[j] = xp[(size_t)j << 10];

  int b = bw >> 4, w = bw & 15;
  float* op = out + ((size_t)b << 20) + (size_t)(w << 10) + (size_t)(t0 + lane);

  const float* A2u = uniform_ptr(A2);
#pragma unroll 2
  for (int c = 0; c < 64; ++c) {
    const float* arow = A2u + (c << 6);
    float a0 = 0.f, a1 = 0.f, a2 = 0.f, a3 = 0.f;
#pragma unroll
    for (int j = 0; j < 64; j += 4) {
      a0 = fmaf(arow[j    ], xv[j    ], a0);
      a1 = fmaf(arow[j + 1], xv[j + 1], a1);
      a2 = fmaf(arow[j + 2], xv[j + 2], a2);
      a3 = fmaf(arow[j + 3], xv[j + 3], a3);
    }
    op[(size_t)c << 14] = (a0 + a1) + (a2 + a3);
  }
}

// ---------------------------------------------------------------------------
extern "C" void kernel_launch(void* const* d_in, const int* in_sizes, int n_in,
                              void* d_out, int out_size, void* d_ws, size_t ws_size,
                              hipStream_t stream) {
  const float* x    = (const float*)d_in[0];
  const float* Wp   = (const float*)d_in[1];
  const float* w1   = (const float*)d_in[2];
  const float* b1   = (const float*)d_in[3];
  const float* w2   = (const float*)d_in[4];
  const float* b2   = (const float*)d_in[5];
  const float* beta = (const float*)d_in[6];
  const float* gres = (const float*)d_in[7];
  const float* temp = (const float*)d_in[8];

  // workspace layout
  double* statT = (double*)d_ws;                                    // 512 KB
  double* Z     = (double*)((char*)d_ws + (512 << 10));             // 32 KB
  float*  A2    = (float*)((char*)d_ws + (512 << 10) + (32 << 10)); // 16 KB

  float* out  = (float*)d_out;
  float* Aout = out + (size_t)B_N * C_N * W_N * T_N;                // 67108864

  k_stats<<<16384, 256, 0, stream>>>(x, statT);
  k_embed<<<1024, 256, 0, stream>>>(statT, Wp, Z);
  k_graph<<<1, 1024, 0, stream>>>(Z, w1, b1, w2, b2, beta, gres, temp, Aout, A2);
  k_prop<<<4096, 256, 0, stream>>>(x, A2, out);
}